// Round 6
// baseline (234.492 us; speedup 1.0000x reference)
//
#include <hip/hip_runtime.h>
#include <cstdint>
#include <cstddef>

typedef short short8 __attribute__((ext_vector_type(8)));
typedef float floatx4 __attribute__((ext_vector_type(4)));
typedef unsigned short ushort4v __attribute__((ext_vector_type(4)));
typedef unsigned int uintx4 __attribute__((ext_vector_type(4)));

constexpr int B_ = 2, S_ = 2048, H_ = 1024, NH_ = 16, DH_ = 64;
constexpr int K_ = H_;        // 1024

__device__ __forceinline__ unsigned short f2bf(float f) {
  unsigned u = __float_as_uint(f);
  u += 0x7fffu + ((u >> 16) & 1u);   // RNE
  return (unsigned short)(u >> 16);
}

// pack two floats to bf16x2 via the HW packed converter (RNE); 1 VALU op vs 5.
__device__ __forceinline__ unsigned cvtpk(float a, float b) {
  unsigned r;
  asm("v_cvt_pk_bf16_f32 %0, %1, %2" : "=v"(r) : "v"(a), "v"(b));
  return r;
}

// ---------------- fused prep: cvt hs / cvt W x3 / bitmask / eam ----------------
// r4 arrangement (measured best): running mask blocks inside gemm cost ~5us
// (they only get ~1 residual block-slot/CU while GEMM blocks are resident).
// Block ranges: [0,1024) hs cvt; [1024,1792) W cvt; [1792,9984) bitmask; 9984 eam.
__global__ __launch_bounds__(256) void prep_kernel(
    const float* __restrict__ hs, unsigned short* __restrict__ hbf,
    const float* __restrict__ Wq, const float* __restrict__ Wk, const float* __restrict__ Wv,
    unsigned short* __restrict__ wqb, unsigned short* __restrict__ wkb,
    unsigned short* __restrict__ wvb,
    const int* __restrict__ lm, unsigned long long* __restrict__ bm,
    const float* __restrict__ am, float* __restrict__ ea) {
  const int bid = blockIdx.x, tid = threadIdx.x;
  if (bid < 1792) {
    const float* in;
    unsigned short* out;
    int off;
    if (bid < 1024) { in = hs; out = hbf; off = bid; }
    else {
      int wsel = (bid - 1024) >> 8;     // 256 blocks per W
      in = (wsel == 0) ? Wq : (wsel == 1) ? Wk : Wv;
      out = (wsel == 0) ? wqb : (wsel == 1) ? wkb : wvb;
      off = (bid - 1024) & 255;
    }
    const int base = off * 4096;   // 4096 elems per block
#pragma unroll
    for (int j = 0; j < 4; j++) {
      int i = base + j * 1024 + tid * 4;   // wave reads 1KB contiguous per round
      float4 v = *reinterpret_cast<const float4*>(in + i);
      ushort4v o;
      o.x = f2bf(v.x); o.y = f2bf(v.y); o.z = f2bf(v.z); o.w = f2bf(v.w);
      *reinterpret_cast<ushort4v*>(out + i) = o;
    }
  } else if (bid < 9984) {
    // 16 words per block: 4 waves x 4 words; coalesced 256B loads per ballot
    const int wbase = (bid - 1792) * 16 + (tid >> 6) * 4;
    const int lane = tid & 63;
#pragma unroll
    for (int j = 0; j < 4; j++) {
      unsigned long long bits = __ballot(lm[(size_t)(wbase + j) * 64 + lane] != 0);
      if (lane == 0) bm[wbase + j] = bits;
    }
  } else {
#pragma unroll
    for (int j = 0; j < 4; j++) {
      int i = j * 1024 + tid * 4;
      float4 v = *reinterpret_cast<const float4*>(am + i);
      float4 o;
      o.x = __expf(v.x); o.y = __expf(v.y); o.z = __expf(v.z); o.w = __expf(v.w);
      *reinterpret_cast<float4*>(ea + i) = o;
    }
  }
}

// ---------------- async global->LDS 16B ----------------
typedef __attribute__((address_space(1))) const void gvoid;
typedef __attribute__((address_space(3))) void lvoid;
__device__ __forceinline__ void async16(const unsigned short* gp, unsigned short* lp) {
  __builtin_amdgcn_global_load_lds((gvoid*)gp, (lvoid*)lp, 16, 0, 0);
}

// ---------------- QKV projection GEMM ----------------
// T3 "minimum 2-phase" K-loop: double-buffered LDS; STAGE(tile kt+1) is issued
// BEFORE compute(tile kt), so the barrier's vmcnt(0) drain at end-of-iter waits
// on loads that had the whole compute phase to land (previously stage->drain->
// compute was fully serial: MfmaUtil 12%, 85% stall). One barrier per K-step.
// z=0 -> q scaled by 0.125*log2(e), layout [B,NH,S,DH]   (TRANSPOSED C)
// z=1 -> K in PERMUTED fragment-tile order (TRANSPOSED C); pi: storage row
//        (t=2T+tau, rr=4q+r) holds true key 32T+8q+4tau+r (native PV B-frag
//        packs in-lane in attention).
// z=2 -> V in native-PV fragment order [dtile][T][quad][l16][jj] (normal C).
__global__ __launch_bounds__(256) void gemm_qkv(
    const unsigned short* __restrict__ A,
    const unsigned short* __restrict__ Wq, const unsigned short* __restrict__ Wk,
    const unsigned short* __restrict__ Wv,
    const float* __restrict__ bq, const float* __restrict__ bk, const float* __restrict__ bv,
    unsigned short* __restrict__ qo, unsigned short* __restrict__ ko,
    unsigned short* __restrict__ vo) {
  __shared__ alignas(16) unsigned short As[2][128 * 32];
  __shared__ alignas(16) unsigned short Bs[2][128 * 32];
  const int z = blockIdx.z;
  const unsigned short* W = (z == 0) ? Wq : (z == 1) ? Wk : Wv;
  const float* bias = (z == 0) ? bq : (z == 1) ? bk : bv;

  const int m0 = blockIdx.x * 128, n0 = blockIdx.y * 128;
  const int tid = threadIdx.x, lane = tid & 63, wvi = tid >> 6;
  const int wr = wvi >> 1, wc = wvi & 1, quad = lane >> 4, l16 = lane & 15;

  floatx4 zf = {0.f, 0.f, 0.f, 0.f};
  floatx4 acc[4][4];
  for (int i = 0; i < 4; i++)
    for (int j = 0; j < 4; j++) acc[i][j] = zf;

  // staging geometry: wave wvi covers LDS element chunks [cb*8, cb*8+512) per i;
  // lane writes 16B at (cb+lane)*8 (DMA dest = wave-uniform base + lane*16B).
  const int cb0 = wvi * 128;        // i=0 chunk base
  const int cb1 = wvi * 128 + 64;   // i=1 chunk base
  const int c0 = cb0 + lane, c1 = cb1 + lane;
  const unsigned short* As0 = A + (size_t)(m0 + (c0 >> 2)) * K_ + (c0 & 3) * 8;
  const unsigned short* As1 = A + (size_t)(m0 + (c1 >> 2)) * K_ + (c1 & 3) * 8;
  const unsigned short* Ws0 = W + (size_t)(n0 + (c0 >> 2)) * K_ + (c0 & 3) * 8;
  const unsigned short* Ws1 = W + (size_t)(n0 + (c1 >> 2)) * K_ + (c1 & 3) * 8;

  // prologue: stage tile 0 into buf 0
  async16(As0, &As[0][cb0 * 8]);
  async16(Ws0, &Bs[0][cb0 * 8]);
  async16(As1, &As[0][cb1 * 8]);
  async16(Ws1, &Bs[0][cb1 * 8]);
  __syncthreads();   // drain tile-0 DMA + publish

  for (int kt = 0; kt < 32; kt++) {
    // ---- STAGE tile kt+1 first (into the buffer last read at iter kt-1;
    //      that reuse is safe: end-of-iter kt-1 barrier drained its readers) ----
    if (kt != 31) {
      const int kk = (kt + 1) * 32;
      const int bn = (kt + 1) & 1;
      async16(As0 + kk, &As[bn][cb0 * 8]);
      async16(Ws0 + kk, &Bs[bn][cb0 * 8]);
      async16(As1 + kk, &As[bn][cb1 * 8]);
      async16(Ws1 + kk, &Bs[bn][cb1 * 8]);
    }
    // ---- compute tile kt from buf[kt&1] ----
    const unsigned short* Ah = As[kt & 1];
    const unsigned short* Bh = Bs[kt & 1];
    short8 af[4], bfr[4];
#pragma unroll
    for (int mf = 0; mf < 4; mf++)
      af[mf] = *reinterpret_cast<const short8*>(&Ah[(wr * 64 + mf * 16 + l16) * 32 + quad * 8]);
#pragma unroll
    for (int nf = 0; nf < 4; nf++)
      bfr[nf] = *reinterpret_cast<const short8*>(&Bh[(wc * 64 + nf * 16 + l16) * 32 + quad * 8]);
    if (z == 2) {
#pragma unroll
      for (int mf = 0; mf < 4; mf++)
#pragma unroll
        for (int nf = 0; nf < 4; nf++)
          acc[mf][nf] = __builtin_amdgcn_mfma_f32_16x16x32_bf16(af[mf], bfr[nf], acc[mf][nf], 0, 0, 0);
    } else {
#pragma unroll
      for (int mf = 0; mf < 4; mf++)
#pragma unroll
        for (int nf = 0; nf < 4; nf++)
          acc[mf][nf] = __builtin_amdgcn_mfma_f32_16x16x32_bf16(bfr[nf], af[mf], acc[mf][nf], 0, 0, 0);
    }
    // one barrier per K-step: drains the kt+1 DMAs (issued before compute, so
    // they had the whole MFMA phase in flight) and publishes buf[(kt+1)&1].
    __syncthreads();
  }

  if (z == 2) {
    // normal C: row = key = m-base + quad*4+r, col = d-row = n-base + l16
    // V layout (true keys): [key64-tile][dtile][T=kl>>5][vq=(kl>>3)&3][l16=d&15][jj=kl&7]
#pragma unroll
    for (int mf = 0; mf < 4; mf++) {
      int mbase = m0 + wr * 64 + mf * 16 + quad * 4;
      int b = mbase >> 11, s0 = mbase & 2047;
      int kl = s0 & 63;   // 4-aligned
#pragma unroll
      for (int nf = 0; nf < 4; nf++) {
        int n = n0 + wc * 64 + nf * 16 + l16;
        int h = n >> 6, d = n & 63;
        int bh = b * NH_ + h;
        float bvv = bias[n];
        floatx4 c = acc[mf][nf];
        size_t base = (size_t)bh * 131072 + (s0 >> 6) * 4096 + (d >> 4) * 1024 +
                      (kl >> 5) * 512 + ((kl >> 3) & 3) * 128 + (d & 15) * 8 + (kl & 7);
        ushort4v p;
        p.x = f2bf(c[0] + bvv); p.y = f2bf(c[1] + bvv);
        p.z = f2bf(c[2] + bvv); p.w = f2bf(c[3] + bvv);
        *reinterpret_cast<ushort4v*>(&vo[base]) = p;
      }
    }
  } else {
    // transposed C: row = d-row = n-base + quad*4+r, col = key/seq = m-base + l16
#pragma unroll
    for (int mf = 0; mf < 4; mf++) {
      int s = m0 + wr * 64 + mf * 16 + l16;   // seq index
      int b = s >> 11;
      int sq = s & 2047;
#pragma unroll
      for (int nf = 0; nf < 4; nf++) {
        int nn = n0 + wc * 64 + nf * 16 + quad * 4;  // d' base, 4-aligned
        int h = nn >> 6, dh = nn & 63;
        int bh = b * NH_ + h;
        float4 b4 = *reinterpret_cast<const float4*>(bias + nn);
        floatx4 c = acc[mf][nf];
        if (z == 0) {
          ushort4v p;
          p.x = f2bf((c[0] + b4.x) * 0.18033688011112042f);  // 0.125*log2(e)
          p.y = f2bf((c[1] + b4.y) * 0.18033688011112042f);
          p.z = f2bf((c[2] + b4.z) * 0.18033688011112042f);
          p.w = f2bf((c[3] + b4.w) * 0.18033688011112042f);
          *reinterpret_cast<ushort4v*>(&qo[((size_t)bh * S_ + sq) * DH_ + dh]) = p;
        } else {
          // K permuted storage: kl -> (t, rr) with t = 2T+tau, rr = 4q+r
          int kl = sq & 63;
          int t = ((kl >> 4) & 2) | ((kl >> 2) & 1);
          int rr = ((kl >> 1) & 12) | (kl & 3);
          size_t base = (size_t)bh * 131072 + (sq >> 6) * 4096 + t * 1024 +
                        (dh >> 5) * 512 + ((dh >> 3) & 3) * 128 + rr * 8 + (dh & 7);
          ushort4v p;
          p.x = f2bf(c[0] + b4.x); p.y = f2bf(c[1] + b4.y);
          p.z = f2bf(c[2] + b4.z); p.w = f2bf(c[3] + b4.w);
          *reinterpret_cast<ushort4v*>(&ko[base]) = p;
        }
      }
    }
  }
}

// ------- dual-softmax flash attention (r1 structure VERBATIM: measured 76.4us;
// both den-MFMA variants (r2/r3) A/B-regressed vs this) -------
__global__ __launch_bounds__(256, 4) void attn_kernel(
    const unsigned short* __restrict__ q,      // [B,NH,S,DH] bf16, scaled log2e/8
    const unsigned short* __restrict__ kperm,  // pi-permuted fragment-tile K
    const unsigned short* __restrict__ vperm,  // native-PV fragment-tile V
    const float* __restrict__ eam,             // [B,S] = exp(amask)
    const unsigned long long* __restrict__ bm, // [B,S,S/64] bitmask
    const float* __restrict__ gate,            // [B,NH,S]
    float* __restrict__ out) {                 // [B,S,H]
  __shared__ alignas(16) unsigned short Ks[2][4096];
  __shared__ alignas(16) unsigned short Vs[2][4096];

  const int flat = blockIdx.x;
  const int h = (flat & 7) + 8 * ((flat >> 3) & 1);
  const int b = (flat >> 4) & 1;
  const int qt = flat >> 5;
  const int tid = threadIdx.x, lane = tid & 63, wvi = tid >> 6;
  const int quad = lane >> 4, l16 = lane & 15;
  const int bh = b * NH_ + h;
  const int q0 = qt * 64 + wvi * 16;  // wave's 16 q-rows; this lane's q = q0+l16
  const int quad8 = quad * 8;

  const unsigned short* qrow = q + ((size_t)bh * S_ + q0 + l16) * DH_;
  short8 qf0 = *reinterpret_cast<const short8*>(qrow + quad * 8);
  short8 qf1 = *reinterpret_cast<const short8*>(qrow + 32 + quad * 8);

  floatx4 zf = {0.f, 0.f, 0.f, 0.f};
  float psg = 0.f, psl = 0.f;
  floatx4 accg[4], accl[4];   // Oᵀ tiles: row d = dtile*16+quad*4+r, col q = l16
#pragma unroll
  for (int i = 0; i < 4; i++) { accg[i] = zf; accl[i] = zf; }

  const unsigned short* kp = kperm + (size_t)bh * 131072;
  const unsigned short* vp = vperm + (size_t)bh * 131072;
  const float* eamb = eam + (size_t)b * S_;
  const unsigned long long* bmq = bm + ((size_t)b * S_ + q0 + l16) * (S_ / 64);

  // staging: thread tid copies tile elems [tid*8,+8) and [2048+tid*8,+8)
  const int soA = tid * 8, soB = 2048 + tid * 8;
  const unsigned short* kgA = kp + soA;
  const unsigned short* kgB = kp + soB;
  const unsigned short* vgA = vp + soA;
  const unsigned short* vgB = vp + soB;

  // prologue: stage tile 0 into buf0; prefetch tile 1 into regs
  uint4 pk0 = *reinterpret_cast<const uint4*>(kgA);
  uint4 pk1 = *reinterpret_cast<const uint4*>(kgB);
  uint4 pv0 = *reinterpret_cast<const uint4*>(vgA);
  uint4 pv1 = *reinterpret_cast<const uint4*>(vgB);
  *reinterpret_cast<uint4*>(&Ks[0][soA]) = pk0;
  *reinterpret_cast<uint4*>(&Ks[0][soB]) = pk1;
  *reinterpret_cast<uint4*>(&Vs[0][soA]) = pv0;
  *reinterpret_cast<uint4*>(&Vs[0][soB]) = pv1;
  pk0 = *reinterpret_cast<const uint4*>(kgA + 4096);
  pk1 = *reinterpret_cast<const uint4*>(kgB + 4096);
  pv0 = *reinterpret_cast<const uint4*>(vgA + 4096);
  pv1 = *reinterpret_cast<const uint4*>(vgB + 4096);

  for (int kt = 0; kt < S_ / 64; kt++) {
    __syncthreads();  // buf[kt&1] visible; buf[(kt+1)&1] readers (iter kt-1) done
    // ---- stage tile kt+1 from regs (conflict-free b128 writes) ----
    {
      const int bn = (kt + 1) & 1;
      *reinterpret_cast<uint4*>(&Ks[bn][soA]) = pk0;
      *reinterpret_cast<uint4*>(&Ks[bn][soB]) = pk1;
      *reinterpret_cast<uint4*>(&Vs[bn][soA]) = pv0;
      *reinterpret_cast<uint4*>(&Vs[bn][soB]) = pv1;
    }
    // ---- prefetch tile kt+2 into regs (wraps; ~full iter of latency slack) ----
    {
      const int tb = ((kt + 2) & 31) * 4096;
      pk0 = *reinterpret_cast<const uint4*>(kgA + tb);
      pk1 = *reinterpret_cast<const uint4*>(kgB + tb);
      pv0 = *reinterpret_cast<const uint4*>(vgA + tb);
      pv1 = *reinterpret_cast<const uint4*>(vgB + tb);
    }
    const int k0 = kt * 64;
    // ---- per-lane mask bits + eam, indexed per pi (issued early) ----
    // lane's keys for tile t=2T+tau: 32T + 8*quad + 4*tau + {0..3}
    uint2 wv = *reinterpret_cast<const uint2*>(&bmq[kt]);
    unsigned wq0 = wv.x >> quad8;           // T=0 half, pre-shifted by quad*8
    unsigned wq1 = wv.y >> quad8;           // T=1 half
    float4 ea0 = *reinterpret_cast<const float4*>(eamb + k0 + quad8);
    float4 ea1 = *reinterpret_cast<const float4*>(eamb + k0 + 4 + quad8);
    float4 ea2 = *reinterpret_cast<const float4*>(eamb + k0 + 32 + quad8);
    float4 ea3 = *reinterpret_cast<const float4*>(eamb + k0 + 36 + quad8);

    const unsigned short* Kc = Ks[kt & 1];
    const unsigned short* Vc = Vs[kt & 1];
    // ---- QKᵀ from LDS (lane-order contiguous b128 reads) ----
    floatx4 scT[4];
#pragma unroll
    for (int t = 0; t < 4; t++) {
      const unsigned short* kr = Kc + t * 1024 + lane * 8;
      short8 kf0 = *reinterpret_cast<const short8*>(kr);
      short8 kf1 = *reinterpret_cast<const short8*>(kr + 512);
      scT[t] = __builtin_amdgcn_mfma_f32_16x16x32_bf16(kf0, qf0, zf, 0, 0, 0);
      scT[t] = __builtin_amdgcn_mfma_f32_16x16x32_bf16(kf1, qf1, scT[t], 0, 0, 0);
    }
    // ---- shared-exp dual softmax (exp2; q carries log2e/8) ----
    // Packs straight into native 16x16x32 B-frags: fgv[T] u32[tau*2+j]
    uintx4 fgv[2], flv[2];
#pragma unroll
    for (int t = 0; t < 4; t++) {
      const int T = t >> 1, tau = t & 1;
      floatx4 sc = scT[t];
      unsigned wq = T ? wq1 : wq0;
      float4 ea = (t == 0) ? ea0 : (t == 1) ? ea1 : (t == 2) ? ea2 : ea3;
      unsigned m4 = (wq >> (tau * 4)) & 0xFu;
      float e0 = __builtin_amdgcn_exp2f(sc[0]);
      float e1 = __builtin_amdgcn_exp2f(sc[1]);
      float e2 = __builtin_amdgcn_exp2f(sc[2]);
      float e3 = __builtin_amdgcn_exp2f(sc[3]);
      float g0 = e0 * ea.x, g1 = e1 * ea.y, g2 = e2 * ea.z, g3 = e3 * ea.w;
      psg += (g0 + g1) + (g2 + g3);
      float l0 = (m4 & 1u) ? e0 : 0.f;
      float l1 = (m4 & 2u) ? e1 : 0.f;
      float l2 = (m4 & 4u) ? e2 : 0.f;
      float l3 = (m4 & 8u) ? e3 : 0.f;
      psl += (l0 + l1) + (l2 + l3);
      fgv[T][tau * 2]     = cvtpk(g0, g1);
      fgv[T][tau * 2 + 1] = cvtpk(g2, g3);
      flv[T][tau * 2]     = cvtpk(l0, l1);
      flv[T][tau * 2 + 1] = cvtpk(l2, l3);
    }
    short8 FG0 = __builtin_bit_cast(short8, fgv[0]);
    short8 FG1 = __builtin_bit_cast(short8, fgv[1]);
    short8 FL0 = __builtin_bit_cast(short8, flv[0]);
    short8 FL1 = __builtin_bit_cast(short8, flv[1]);
    // ---- PV from LDS: Oᵀ += Vᵀ·P, native 16x16x32 (b128 reads) ----
#pragma unroll
    for (int d = 0; d < 4; d++) {
      const unsigned short* vb = Vc + d * 1024 + lane * 8;
      short8 v0 = *reinterpret_cast<const short8*>(vb);        // T=0: keys 0..31
      short8 v1 = *reinterpret_cast<const short8*>(vb + 512);  // T=1: keys 32..63
      accg[d] = __builtin_amdgcn_mfma_f32_16x16x32_bf16(v0, FG0, accg[d], 0, 0, 0);
      accl[d] = __builtin_amdgcn_mfma_f32_16x16x32_bf16(v0, FL0, accl[d], 0, 0, 0);
      accg[d] = __builtin_amdgcn_mfma_f32_16x16x32_bf16(v1, FG1, accg[d], 0, 0, 0);
      accl[d] = __builtin_amdgcn_mfma_f32_16x16x32_bf16(v1, FL1, accl[d], 0, 0, 0);
    }
  }

  // ---- epilogue: quad-reduce denominators, gate-combine, float4 stores ----
  float lgf = psg;
  lgf += __shfl_xor(lgf, 16, 64);
  lgf += __shfl_xor(lgf, 32, 64);
  float llf = psl;
  llf += __shfl_xor(llf, 16, 64);
  llf += __shfl_xor(llf, 32, 64);
  const int s = q0 + l16;
  const float g = gate[(size_t)bh * S_ + s];
  const float cg = (1.f - g) / lgf, cl = g / llf;
  float* orow = out + ((size_t)b * S_ + s) * H_ + h * DH_ + quad * 4;
#pragma unroll
  for (int d = 0; d < 4; d++) {
    float4 o;
    o.x = cl * accl[d][0] + cg * accg[d][0];
    o.y = cl * accl[d][1] + cg * accg[d][1];
    o.z = cl * accl[d][2] + cg * accg[d][2];
    o.w = cl * accl[d][3] + cg * accg[d][3];
    *reinterpret_cast<float4*>(orow + d * 16) = o;
  }
}

extern "C" void kernel_launch(void* const* d_in, const int* in_sizes, int n_in,
                              void* d_out, int out_size, void* d_ws, size_t ws_size,
                              hipStream_t stream) {
  (void)in_sizes; (void)n_in; (void)out_size; (void)ws_size;
  const float* hs = (const float*)d_in[0];
  const float* am = (const float*)d_in[1];
  const int* lm = (const int*)d_in[2];
  const float* gate = (const float*)d_in[3];
  const float* Wq = (const float*)d_in[4];
  const float* bq = (const float*)d_in[5];
  const float* Wk = (const float*)d_in[6];
  const float* bk = (const float*)d_in[7];
  const float* Wv = (const float*)d_in[8];
  const float* bv = (const float*)d_in[9];
  float* out = (float*)d_out;

  unsigned short* ws = (unsigned short*)d_ws;
  unsigned short* hbf = ws;                  // 4,194,304 elems
  unsigned short* wqb = hbf + 4194304;       // 1,048,576
  unsigned short* wkb = wqb + 1048576;
  unsigned short* wvb = wkb + 1048576;
  unsigned short* qb = wvb + 1048576;        // 4,194,304
  unsigned short* kb = qb + 4194304;
  unsigned short* vtb = kb + 4194304;
  unsigned long long* bmp = (unsigned long long*)(vtb + 4194304);  // 1 MB
  float* eamp = (float*)(bmp + 131072);      // 4096 floats

  prep_kernel<<<9985, 256, 0, stream>>>(hs, hbf, Wq, Wk, Wv, wqb, wkb, wvb, lm, bmp, am, eamp);
  gemm_qkv<<<dim3(32, 8, 3), 256, 0, stream>>>(hbf, wqb, wkb, wvb, bq, bk, bv, qb, kb, vtb);
  attn_kernel<<<dim3(1024), 256, 0, stream>>>(qb, kb, vtb, eamp, bmp, gate, out);
}

// Round 7
// 228.388 us; speedup vs baseline: 1.0267x; 1.0267x over previous
//
#include <hip/hip_runtime.h>
#include <cstdint>
#include <cstddef>

typedef short short8 __attribute__((ext_vector_type(8)));
typedef float floatx4 __attribute__((ext_vector_type(4)));
typedef unsigned short ushort4v __attribute__((ext_vector_type(4)));
typedef unsigned int uintx4 __attribute__((ext_vector_type(4)));

constexpr int B_ = 2, S_ = 2048, H_ = 1024, NH_ = 16, DH_ = 64;
constexpr int K_ = H_;        // 1024

__device__ __forceinline__ unsigned short f2bf(float f) {
  unsigned u = __float_as_uint(f);
  u += 0x7fffu + ((u >> 16) & 1u);   // RNE
  return (unsigned short)(u >> 16);
}

// pack two floats to bf16x2 via the HW packed converter (RNE); 1 VALU op vs 5.
__device__ __forceinline__ unsigned cvtpk(float a, float b) {
  unsigned r;
  asm("v_cvt_pk_bf16_f32 %0, %1, %2" : "=v"(r) : "v"(a), "v"(b));
  return r;
}

// ---------------- fused prep: cvt hs / cvt W x3 / bitmask / eam ----------------
// r4 arrangement (measured best across r4-r6).
// Block ranges: [0,1024) hs cvt; [1024,1792) W cvt; [1792,9984) bitmask; 9984 eam.
__global__ __launch_bounds__(256) void prep_kernel(
    const float* __restrict__ hs, unsigned short* __restrict__ hbf,
    const float* __restrict__ Wq, const float* __restrict__ Wk, const float* __restrict__ Wv,
    unsigned short* __restrict__ wqb, unsigned short* __restrict__ wkb,
    unsigned short* __restrict__ wvb,
    const int* __restrict__ lm, unsigned long long* __restrict__ bm,
    const float* __restrict__ am, float* __restrict__ ea) {
  const int bid = blockIdx.x, tid = threadIdx.x;
  if (bid < 1792) {
    const float* in;
    unsigned short* out;
    int off;
    if (bid < 1024) { in = hs; out = hbf; off = bid; }
    else {
      int wsel = (bid - 1024) >> 8;     // 256 blocks per W
      in = (wsel == 0) ? Wq : (wsel == 1) ? Wk : Wv;
      out = (wsel == 0) ? wqb : (wsel == 1) ? wkb : wvb;
      off = (bid - 1024) & 255;
    }
    const int base = off * 4096;   // 4096 elems per block
#pragma unroll
    for (int j = 0; j < 4; j++) {
      int i = base + j * 1024 + tid * 4;   // wave reads 1KB contiguous per round
      float4 v = *reinterpret_cast<const float4*>(in + i);
      ushort4v o;
      o.x = f2bf(v.x); o.y = f2bf(v.y); o.z = f2bf(v.z); o.w = f2bf(v.w);
      *reinterpret_cast<ushort4v*>(out + i) = o;
    }
  } else if (bid < 9984) {
    // 16 words per block: 4 waves x 4 words; coalesced 256B loads per ballot
    const int wbase = (bid - 1792) * 16 + (tid >> 6) * 4;
    const int lane = tid & 63;
#pragma unroll
    for (int j = 0; j < 4; j++) {
      unsigned long long bits = __ballot(lm[(size_t)(wbase + j) * 64 + lane] != 0);
      if (lane == 0) bm[wbase + j] = bits;
    }
  } else {
#pragma unroll
    for (int j = 0; j < 4; j++) {
      int i = j * 1024 + tid * 4;
      float4 v = *reinterpret_cast<const float4*>(am + i);
      float4 o;
      o.x = __expf(v.x); o.y = __expf(v.y); o.z = __expf(v.z); o.w = __expf(v.w);
      *reinterpret_cast<float4*>(ea + i) = o;
    }
  }
}

// ---------------- async global->LDS 16B ----------------
typedef __attribute__((address_space(1))) const void gvoid;
typedef __attribute__((address_space(3))) void lvoid;
__device__ __forceinline__ void async16(const unsigned short* gp, unsigned short* lp) {
  __builtin_amdgcn_global_load_lds((gvoid*)gp, (lvoid*)lp, 16, 0, 0);
}

// ---------------- QKV projection GEMM: counted-vmcnt 3-deep pipeline ----------
// T3+T4: tiles kt,kt+1,kt+2 in flight (12 DMAs/wave); per iter wait only the
// OLDEST tile (s_waitcnt vmcnt(8)) + raw s_barrier — never drain to 0 in the
// main loop. Each tile's DMA gets ~3 iterations of latency slack (was <1 with
// __syncthreads' implicit vmcnt(0): MfmaUtil 12%, ~85% stall). Per-wave vmcnt
// covers that wave's own 4 stage-DMAs; the barrier makes completion collective.
// z=0 -> q scaled by 0.125*log2(e), layout [B,NH,S,DH]   (TRANSPOSED C)
// z=1 -> K in PERMUTED fragment-tile order (TRANSPOSED C); pi: storage row
//        (t=2T+tau, rr=4q+r) holds true key 32T+8q+4tau+r.
// z=2 -> V in native-PV fragment order [dtile][T][quad][l16][jj] (normal C).
__global__ __launch_bounds__(256) void gemm_qkv(
    const unsigned short* __restrict__ A,
    const unsigned short* __restrict__ Wq, const unsigned short* __restrict__ Wk,
    const unsigned short* __restrict__ Wv,
    const float* __restrict__ bq, const float* __restrict__ bk, const float* __restrict__ bv,
    unsigned short* __restrict__ qo, unsigned short* __restrict__ ko,
    unsigned short* __restrict__ vo) {
  __shared__ alignas(16) unsigned short As[3][128 * 32];
  __shared__ alignas(16) unsigned short Bs[3][128 * 32];
  const int z = blockIdx.z;
  const unsigned short* W = (z == 0) ? Wq : (z == 1) ? Wk : Wv;
  const float* bias = (z == 0) ? bq : (z == 1) ? bk : bv;

  const int m0 = blockIdx.x * 128, n0 = blockIdx.y * 128;
  const int tid = threadIdx.x, lane = tid & 63, wvi = tid >> 6;
  const int wr = wvi >> 1, wc = wvi & 1, quad = lane >> 4, l16 = lane & 15;

  floatx4 zf = {0.f, 0.f, 0.f, 0.f};
  floatx4 acc[4][4];
  for (int i = 0; i < 4; i++)
    for (int j = 0; j < 4; j++) acc[i][j] = zf;

  // staging geometry: wave wvi covers LDS element chunks [cb*8, cb*8+512) per
  // call; DMA dest = wave-uniform base + lane*16B; rows wvi*32..wvi*32+31.
  const int cb0 = wvi * 128;        // chunk base 0
  const int cb1 = wvi * 128 + 64;   // chunk base 1
  const int c0 = cb0 + lane, c1 = cb1 + lane;
  const unsigned short* As0 = A + (size_t)(m0 + (c0 >> 2)) * K_ + (c0 & 3) * 8;
  const unsigned short* As1 = A + (size_t)(m0 + (c1 >> 2)) * K_ + (c1 & 3) * 8;
  const unsigned short* Ws0 = W + (size_t)(n0 + (c0 >> 2)) * K_ + (c0 & 3) * 8;
  const unsigned short* Ws1 = W + (size_t)(n0 + (c1 >> 2)) * K_ + (c1 & 3) * 8;

  // 4 DMA instructions per wave per tile — vmcnt counts these per-wave.
  auto STAGE = [&](int t) {
    const int bn = t % 3;
    const int kk = t * 32;
    async16(As0 + kk, &As[bn][cb0 * 8]);
    async16(Ws0 + kk, &Bs[bn][cb0 * 8]);
    async16(As1 + kk, &As[bn][cb1 * 8]);
    async16(Ws1 + kk, &Bs[bn][cb1 * 8]);
  };
  auto COMPUTE = [&](int kt) {
    const unsigned short* Ah = As[kt % 3];
    const unsigned short* Bh = Bs[kt % 3];
    short8 af[4], bfr[4];
#pragma unroll
    for (int mf = 0; mf < 4; mf++)
      af[mf] = *reinterpret_cast<const short8*>(&Ah[(wr * 64 + mf * 16 + l16) * 32 + quad * 8]);
#pragma unroll
    for (int nf = 0; nf < 4; nf++)
      bfr[nf] = *reinterpret_cast<const short8*>(&Bh[(wc * 64 + nf * 16 + l16) * 32 + quad * 8]);
    if (z == 2) {
#pragma unroll
      for (int mf = 0; mf < 4; mf++)
#pragma unroll
        for (int nf = 0; nf < 4; nf++)
          acc[mf][nf] = __builtin_amdgcn_mfma_f32_16x16x32_bf16(af[mf], bfr[nf], acc[mf][nf], 0, 0, 0);
    } else {
#pragma unroll
      for (int mf = 0; mf < 4; mf++)
#pragma unroll
        for (int nf = 0; nf < 4; nf++)
          acc[mf][nf] = __builtin_amdgcn_mfma_f32_16x16x32_bf16(bfr[nf], af[mf], acc[mf][nf], 0, 0, 0);
    }
  };

  // prologue: 3 tiles in flight
  STAGE(0); STAGE(1); STAGE(2);

  // main loop: wait oldest tile only (12 outstanding -> 8), compute, free, refill
  for (int kt = 0; kt < 29; kt++) {
    asm volatile("s_waitcnt vmcnt(8)" ::: "memory");
    __builtin_amdgcn_s_barrier();     // tile kt complete in ALL waves
    COMPUTE(kt);
    __builtin_amdgcn_s_barrier();     // all waves done reading buf[kt%3]
    STAGE(kt + 3);                    // refill freed buffer
  }
  // tail: outstanding 12 -> 8 -> 4 -> 0
  asm volatile("s_waitcnt vmcnt(8)" ::: "memory");
  __builtin_amdgcn_s_barrier();
  COMPUTE(29);
  __builtin_amdgcn_s_barrier();
  asm volatile("s_waitcnt vmcnt(4)" ::: "memory");
  __builtin_amdgcn_s_barrier();
  COMPUTE(30);
  __builtin_amdgcn_s_barrier();
  asm volatile("s_waitcnt vmcnt(0)" ::: "memory");
  __builtin_amdgcn_s_barrier();
  COMPUTE(31);

  if (z == 2) {
    // normal C: row = key = m-base + quad*4+r, col = d-row = n-base + l16
    // V layout (true keys): [key64-tile][dtile][T=kl>>5][vq=(kl>>3)&3][l16=d&15][jj=kl&7]
#pragma unroll
    for (int mf = 0; mf < 4; mf++) {
      int mbase = m0 + wr * 64 + mf * 16 + quad * 4;
      int b = mbase >> 11, s0 = mbase & 2047;
      int kl = s0 & 63;   // 4-aligned
#pragma unroll
      for (int nf = 0; nf < 4; nf++) {
        int n = n0 + wc * 64 + nf * 16 + l16;
        int h = n >> 6, d = n & 63;
        int bh = b * NH_ + h;
        float bvv = bias[n];
        floatx4 c = acc[mf][nf];
        size_t base = (size_t)bh * 131072 + (s0 >> 6) * 4096 + (d >> 4) * 1024 +
                      (kl >> 5) * 512 + ((kl >> 3) & 3) * 128 + (d & 15) * 8 + (kl & 7);
        ushort4v p;
        p.x = f2bf(c[0] + bvv); p.y = f2bf(c[1] + bvv);
        p.z = f2bf(c[2] + bvv); p.w = f2bf(c[3] + bvv);
        *reinterpret_cast<ushort4v*>(&vo[base]) = p;
      }
    }
  } else {
    // transposed C: row = d-row = n-base + quad*4+r, col = key/seq = m-base + l16
#pragma unroll
    for (int mf = 0; mf < 4; mf++) {
      int s = m0 + wr * 64 + mf * 16 + l16;   // seq index
      int b = s >> 11;
      int sq = s & 2047;
#pragma unroll
      for (int nf = 0; nf < 4; nf++) {
        int nn = n0 + wc * 64 + nf * 16 + quad * 4;  // d' base, 4-aligned
        int h = nn >> 6, dh = nn & 63;
        int bh = b * NH_ + h;
        float4 b4 = *reinterpret_cast<const float4*>(bias + nn);
        floatx4 c = acc[mf][nf];
        if (z == 0) {
          ushort4v p;
          p.x = f2bf((c[0] + b4.x) * 0.18033688011112042f);  // 0.125*log2(e)
          p.y = f2bf((c[1] + b4.y) * 0.18033688011112042f);
          p.z = f2bf((c[2] + b4.z) * 0.18033688011112042f);
          p.w = f2bf((c[3] + b4.w) * 0.18033688011112042f);
          *reinterpret_cast<ushort4v*>(&qo[((size_t)bh * S_ + sq) * DH_ + dh]) = p;
        } else {
          // K permuted storage: kl -> (t, rr) with t = 2T+tau, rr = 4q+r
          int kl = sq & 63;
          int t = ((kl >> 4) & 2) | ((kl >> 2) & 1);
          int rr = ((kl >> 1) & 12) | (kl & 3);
          size_t base = (size_t)bh * 131072 + (sq >> 6) * 4096 + t * 1024 +
                        (dh >> 5) * 512 + ((dh >> 3) & 3) * 128 + rr * 8 + (dh & 7);
          ushort4v p;
          p.x = f2bf(c[0] + b4.x); p.y = f2bf(c[1] + b4.y);
          p.z = f2bf(c[2] + b4.z); p.w = f2bf(c[3] + b4.w);
          *reinterpret_cast<ushort4v*>(&ko[base]) = p;
        }
      }
    }
  }
}

// ------- dual-softmax flash attention (r1 structure VERBATIM: measured 76.4us;
// both den-MFMA variants (r2/r3) A/B-regressed vs this) -------
__global__ __launch_bounds__(256, 4) void attn_kernel(
    const unsigned short* __restrict__ q,      // [B,NH,S,DH] bf16, scaled log2e/8
    const unsigned short* __restrict__ kperm,  // pi-permuted fragment-tile K
    const unsigned short* __restrict__ vperm,  // native-PV fragment-tile V
    const float* __restrict__ eam,             // [B,S] = exp(amask)
    const unsigned long long* __restrict__ bm, // [B,S,S/64] bitmask
    const float* __restrict__ gate,            // [B,NH,S]
    float* __restrict__ out) {                 // [B,S,H]
  __shared__ alignas(16) unsigned short Ks[2][4096];
  __shared__ alignas(16) unsigned short Vs[2][4096];

  const int flat = blockIdx.x;
  const int h = (flat & 7) + 8 * ((flat >> 3) & 1);
  const int b = (flat >> 4) & 1;
  const int qt = flat >> 5;
  const int tid = threadIdx.x, lane = tid & 63, wvi = tid >> 6;
  const int quad = lane >> 4, l16 = lane & 15;
  const int bh = b * NH_ + h;
  const int q0 = qt * 64 + wvi * 16;  // wave's 16 q-rows; this lane's q = q0+l16
  const int quad8 = quad * 8;

  const unsigned short* qrow = q + ((size_t)bh * S_ + q0 + l16) * DH_;
  short8 qf0 = *reinterpret_cast<const short8*>(qrow + quad * 8);
  short8 qf1 = *reinterpret_cast<const short8*>(qrow + 32 + quad * 8);

  floatx4 zf = {0.f, 0.f, 0.f, 0.f};
  float psg = 0.f, psl = 0.f;
  floatx4 accg[4], accl[4];   // Oᵀ tiles: row d = dtile*16+quad*4+r, col q = l16
#pragma unroll
  for (int i = 0; i < 4; i++) { accg[i] = zf; accl[i] = zf; }

  const unsigned short* kp = kperm + (size_t)bh * 131072;
  const unsigned short* vp = vperm + (size_t)bh * 131072;
  const float* eamb = eam + (size_t)b * S_;
  const unsigned long long* bmq = bm + ((size_t)b * S_ + q0 + l16) * (S_ / 64);

  // staging: thread tid copies tile elems [tid*8,+8) and [2048+tid*8,+8)
  const int soA = tid * 8, soB = 2048 + tid * 8;
  const unsigned short* kgA = kp + soA;
  const unsigned short* kgB = kp + soB;
  const unsigned short* vgA = vp + soA;
  const unsigned short* vgB = vp + soB;

  // prologue: stage tile 0 into buf0; prefetch tile 1 into regs
  uint4 pk0 = *reinterpret_cast<const uint4*>(kgA);
  uint4 pk1 = *reinterpret_cast<const uint4*>(kgB);
  uint4 pv0 = *reinterpret_cast<const uint4*>(vgA);
  uint4 pv1 = *reinterpret_cast<const uint4*>(vgB);
  *reinterpret_cast<uint4*>(&Ks[0][soA]) = pk0;
  *reinterpret_cast<uint4*>(&Ks[0][soB]) = pk1;
  *reinterpret_cast<uint4*>(&Vs[0][soA]) = pv0;
  *reinterpret_cast<uint4*>(&Vs[0][soB]) = pv1;
  pk0 = *reinterpret_cast<const uint4*>(kgA + 4096);
  pk1 = *reinterpret_cast<const uint4*>(kgB + 4096);
  pv0 = *reinterpret_cast<const uint4*>(vgA + 4096);
  pv1 = *reinterpret_cast<const uint4*>(vgB + 4096);

  for (int kt = 0; kt < S_ / 64; kt++) {
    __syncthreads();  // buf[kt&1] visible; buf[(kt+1)&1] readers (iter kt-1) done
    // ---- stage tile kt+1 from regs (conflict-free b128 writes) ----
    {
      const int bn = (kt + 1) & 1;
      *reinterpret_cast<uint4*>(&Ks[bn][soA]) = pk0;
      *reinterpret_cast<uint4*>(&Ks[bn][soB]) = pk1;
      *reinterpret_cast<uint4*>(&Vs[bn][soA]) = pv0;
      *reinterpret_cast<uint4*>(&Vs[bn][soB]) = pv1;
    }
    // ---- prefetch tile kt+2 into regs (wraps; ~full iter of latency slack) ----
    {
      const int tb = ((kt + 2) & 31) * 4096;
      pk0 = *reinterpret_cast<const uint4*>(kgA + tb);
      pk1 = *reinterpret_cast<const uint4*>(kgB + tb);
      pv0 = *reinterpret_cast<const uint4*>(vgA + tb);
      pv1 = *reinterpret_cast<const uint4*>(vgB + tb);
    }
    const int k0 = kt * 64;
    // ---- per-lane mask bits + eam, indexed per pi (issued early) ----
    // lane's keys for tile t=2T+tau: 32T + 8*quad + 4*tau + {0..3}
    uint2 wv = *reinterpret_cast<const uint2*>(&bmq[kt]);
    unsigned wq0 = wv.x >> quad8;           // T=0 half, pre-shifted by quad*8
    unsigned wq1 = wv.y >> quad8;           // T=1 half
    float4 ea0 = *reinterpret_cast<const float4*>(eamb + k0 + quad8);
    float4 ea1 = *reinterpret_cast<const float4*>(eamb + k0 + 4 + quad8);
    float4 ea2 = *reinterpret_cast<const float4*>(eamb + k0 + 32 + quad8);
    float4 ea3 = *reinterpret_cast<const float4*>(eamb + k0 + 36 + quad8);

    const unsigned short* Kc = Ks[kt & 1];
    const unsigned short* Vc = Vs[kt & 1];
    // ---- QKᵀ from LDS (lane-order contiguous b128 reads) ----
    floatx4 scT[4];
#pragma unroll
    for (int t = 0; t < 4; t++) {
      const unsigned short* kr = Kc + t * 1024 + lane * 8;
      short8 kf0 = *reinterpret_cast<const short8*>(kr);
      short8 kf1 = *reinterpret_cast<const short8*>(kr + 512);
      scT[t] = __builtin_amdgcn_mfma_f32_16x16x32_bf16(kf0, qf0, zf, 0, 0, 0);
      scT[t] = __builtin_amdgcn_mfma_f32_16x16x32_bf16(kf1, qf1, scT[t], 0, 0, 0);
    }
    // ---- shared-exp dual softmax (exp2; q carries log2e/8) ----
    // Packs straight into native 16x16x32 B-frags: fgv[T] u32[tau*2+j]
    uintx4 fgv[2], flv[2];
#pragma unroll
    for (int t = 0; t < 4; t++) {
      const int T = t >> 1, tau = t & 1;
      floatx4 sc = scT[t];
      unsigned wq = T ? wq1 : wq0;
      float4 ea = (t == 0) ? ea0 : (t == 1) ? ea1 : (t == 2) ? ea2 : ea3;
      unsigned m4 = (wq >> (tau * 4)) & 0xFu;
      float e0 = __builtin_amdgcn_exp2f(sc[0]);
      float e1 = __builtin_amdgcn_exp2f(sc[1]);
      float e2 = __builtin_amdgcn_exp2f(sc[2]);
      float e3 = __builtin_amdgcn_exp2f(sc[3]);
      float g0 = e0 * ea.x, g1 = e1 * ea.y, g2 = e2 * ea.z, g3 = e3 * ea.w;
      psg += (g0 + g1) + (g2 + g3);
      float l0 = (m4 & 1u) ? e0 : 0.f;
      float l1 = (m4 & 2u) ? e1 : 0.f;
      float l2 = (m4 & 4u) ? e2 : 0.f;
      float l3 = (m4 & 8u) ? e3 : 0.f;
      psl += (l0 + l1) + (l2 + l3);
      fgv[T][tau * 2]     = cvtpk(g0, g1);
      fgv[T][tau * 2 + 1] = cvtpk(g2, g3);
      flv[T][tau * 2]     = cvtpk(l0, l1);
      flv[T][tau * 2 + 1] = cvtpk(l2, l3);
    }
    short8 FG0 = __builtin_bit_cast(short8, fgv[0]);
    short8 FG1 = __builtin_bit_cast(short8, fgv[1]);
    short8 FL0 = __builtin_bit_cast(short8, flv[0]);
    short8 FL1 = __builtin_bit_cast(short8, flv[1]);
    // ---- PV from LDS: Oᵀ += Vᵀ·P, native 16x16x32 (b128 reads) ----
#pragma unroll
    for (int d = 0; d < 4; d++) {
      const unsigned short* vb = Vc + d * 1024 + lane * 8;
      short8 v0 = *reinterpret_cast<const short8*>(vb);        // T=0: keys 0..31
      short8 v1 = *reinterpret_cast<const short8*>(vb + 512);  // T=1: keys 32..63
      accg[d] = __builtin_amdgcn_mfma_f32_16x16x32_bf16(v0, FG0, accg[d], 0, 0, 0);
      accl[d] = __builtin_amdgcn_mfma_f32_16x16x32_bf16(v0, FL0, accl[d], 0, 0, 0);
      accg[d] = __builtin_amdgcn_mfma_f32_16x16x32_bf16(v1, FG1, accg[d], 0, 0, 0);
      accl[d] = __builtin_amdgcn_mfma_f32_16x16x32_bf16(v1, FL1, accl[d], 0, 0, 0);
    }
  }

  // ---- epilogue: quad-reduce denominators, gate-combine, float4 stores ----
  float lgf = psg;
  lgf += __shfl_xor(lgf, 16, 64);
  lgf += __shfl_xor(lgf, 32, 64);
  float llf = psl;
  llf += __shfl_xor(llf, 16, 64);
  llf += __shfl_xor(llf, 32, 64);
  const int s = q0 + l16;
  const float g = gate[(size_t)bh * S_ + s];
  const float cg = (1.f - g) / lgf, cl = g / llf;
  float* orow = out + ((size_t)b * S_ + s) * H_ + h * DH_ + quad * 4;
#pragma unroll
  for (int d = 0; d < 4; d++) {
    float4 o;
    o.x = cl * accl[d][0] + cg * accg[d][0];
    o.y = cl * accl[d][1] + cg * accg[d][1];
    o.z = cl * accl[d][2] + cg * accg[d][2];
    o.w = cl * accl[d][3] + cg * accg[d][3];
    *reinterpret_cast<float4*>(orow + d * 16) = o;
  }
}

extern "C" void kernel_launch(void* const* d_in, const int* in_sizes, int n_in,
                              void* d_out, int out_size, void* d_ws, size_t ws_size,
                              hipStream_t stream) {
  (void)in_sizes; (void)n_in; (void)out_size; (void)ws_size;
  const float* hs = (const float*)d_in[0];
  const float* am = (const float*)d_in[1];
  const int* lm = (const int*)d_in[2];
  const float* gate = (const float*)d_in[3];
  const float* Wq = (const float*)d_in[4];
  const float* bq = (const float*)d_in[5];
  const float* Wk = (const float*)d_in[6];
  const float* bk = (const float*)d_in[7];
  const float* Wv = (const float*)d_in[8];
  const float* bv = (const float*)d_in[9];
  float* out = (float*)d_out;

  unsigned short* ws = (unsigned short*)d_ws;
  unsigned short* hbf = ws;                  // 4,194,304 elems
  unsigned short* wqb = hbf + 4194304;       // 1,048,576
  unsigned short* wkb = wqb + 1048576;
  unsigned short* wvb = wkb + 1048576;
  unsigned short* qb = wvb + 1048576;        // 4,194,304
  unsigned short* kb = qb + 4194304;
  unsigned short* vtb = kb + 4194304;
  unsigned long long* bmp = (unsigned long long*)(vtb + 4194304);  // 1 MB
  float* eamp = (float*)(bmp + 131072);      // 4096 floats

  prep_kernel<<<9985, 256, 0, stream>>>(hs, hbf, Wq, Wk, Wv, wqb, wkb, wvb, lm, bmp, am, eamp);
  gemm_qkv<<<dim3(32, 8, 3), 256, 0, stream>>>(hbf, wqb, wkb, wvb, bq, bk, bv, qb, kb, vtb);
  attn_kernel<<<dim3(1024), 256, 0, stream>>>(qb, kb, vtb, eamp, bmp, gate, out);
}